// Round 9
// baseline (615.692 us; speedup 1.0000x reference)
//
#include <hip/hip_runtime.h>
#include <hip/hip_bf16.h>
#include <stdint.h>

// Problem constants (fixed by the reference)
#define NN   50000
#define RR   50
#define BB   30
#define DIN  64
#define EE   1000000
#define KTOT (BB*DIN + DIN)   // 1984 = 62*32
#define NBW  16               // nodes per workgroup; 50000 = 3125*16 exactly
#define ROWE (KTOT + 8)       // padded LDS row: 1992 elems (3984 B)
#define CPAD 32               // comp row padded 30 -> 32 floats (128 B)
#define EPAD (EE + 8*NN + 32) // ep entries incl. per-node 8-alignment ghosts

typedef __attribute__((ext_vector_type(8))) short short8;
typedef __attribute__((ext_vector_type(4))) float floatx4;

#define RFL(x) __builtin_amdgcn_readfirstlane(x)

// ---------------- preprocessing: counting sort of edges by dst ----------------

__global__ void k_hist(const int* __restrict__ dst, const int* __restrict__ et,
                       int* __restrict__ cnt) {
    int e = blockIdx.x * 256 + threadIdx.x;
    if (e < EE) {
        int d = dst[e], r = et[e];
        atomicAdd(&cnt[d * RR + r], 1);
    }
}

// derive dcount from cnt rows; PAD each node's segment to a multiple of 8
__global__ void k_scan1(const int* __restrict__ cnt, int* __restrict__ dcount,
                        int* __restrict__ doff, int* __restrict__ bsum) {
    __shared__ int sh[256];
    int t = threadIdx.x;
    int i = blockIdx.x * 256 + t;
    int vp = 0;
    if (i < NN) {
        const int* c = cnt + (size_t)i * RR;
        int v = 0;
#pragma unroll
        for (int r = 0; r < RR; ++r) v += c[r];
        vp = (v + 7) & ~7;
        dcount[i] = vp;
    }
    sh[t] = vp;
    __syncthreads();
    for (int s = 1; s < 256; s <<= 1) {
        int add = (t >= s) ? sh[t - s] : 0;
        __syncthreads();
        sh[t] += add;
        __syncthreads();
    }
    int incl = sh[t];
    if (i < NN) doff[i] = incl - vp;
    if (t == 255) bsum[blockIdx.x] = incl;
}

__global__ void k_scan2(int* __restrict__ bsum, int nbv) {
    __shared__ int sh[256];
    int t = threadIdx.x;
    int v = (t < nbv) ? bsum[t] : 0;
    sh[t] = v;
    __syncthreads();
    for (int s = 1; s < 256; s <<= 1) {
        int add = (t >= s) ? sh[t - s] : 0;
        __syncthreads();
        sh[t] += add;
        __syncthreads();
    }
    if (t < nbv) bsum[t] = sh[t] - v;
}

__global__ void k_scan3(int* __restrict__ doff, const int* __restrict__ bsum) {
    int i = blockIdx.x * 256 + threadIdx.x;
    if (i < NN) doff[i] += bsum[blockIdx.x];
}

// record (4 B): src[15:0] | rel[21:16] | cnt[29:22]; ghosts are all-zero
// (cnt==0 -> rcp LUT gives a=0 -> exact no-op edge)
__global__ void k_scatter(const int* __restrict__ src, const int* __restrict__ dst,
                          const int* __restrict__ et, const int* __restrict__ cnt,
                          const int* __restrict__ doff, int* __restrict__ cursor,
                          int* __restrict__ ep) {
    int e = blockIdx.x * 256 + threadIdx.x;
    if (e < EE) {
        int d = dst[e], r = et[e], s = src[e];
        int p = doff[d] + atomicAdd(&cursor[d], 1);
        int c = cnt[d * RR + r]; c = (c > 255) ? 255 : c;
        ep[p] = s | (r << 16) | (c << 22);
    }
}

// ---------------- degree counting-sort (descending) for wave balance ----------

__global__ void k_deghist(const int* __restrict__ dcount, int* __restrict__ dbin) {
    __shared__ int lh[256];
    int t = threadIdx.x;
    int i = blockIdx.x * 256 + t;
    lh[t] = 0;
    __syncthreads();
    if (i < NN) {
        int d = dcount[i]; d = (d > 255) ? 255 : d;
        atomicAdd(&lh[255 - d], 1);
    }
    __syncthreads();
    if (lh[t]) atomicAdd(&dbin[t], lh[t]);
}

__global__ void k_degscan(int* __restrict__ dbin) {
    __shared__ int sh[256];
    int t = threadIdx.x;
    int v = dbin[t];
    sh[t] = v;
    __syncthreads();
    for (int s = 1; s < 256; s <<= 1) {
        int add = (t >= s) ? sh[t - s] : 0;
        __syncthreads();
        sh[t] += add;
        __syncthreads();
    }
    dbin[t] = sh[t] - v;
}

__global__ void k_degscatter(const int* __restrict__ dcount, const int* __restrict__ dbin,
                             int* __restrict__ dcur, int* __restrict__ order) {
    __shared__ int lh[256], lbase[256];
    int t = threadIdx.x;
    int i = blockIdx.x * 256 + t;
    lh[t] = 0;
    __syncthreads();
    int b = 0, lpos = 0;
    if (i < NN) {
        int d = dcount[i]; d = (d > 255) ? 255 : d;
        b = 255 - d;
        lpos = atomicAdd(&lh[b], 1);
    }
    __syncthreads();
    lbase[t] = lh[t] ? atomicAdd(&dcur[t], lh[t]) : 0;
    __syncthreads();
    if (i < NN) order[dbin[b] + lbase[b] + lpos] = i;
}

// x f32 -> int8 with per-node row scale (one wave per node)
__global__ void k_quant_x(const float* __restrict__ x, signed char* __restrict__ xq,
                          float* __restrict__ xs) {
    const int wv = threadIdx.x >> 6, lane = threadIdx.x & 63;
    const int n = blockIdx.x * 4 + wv;
    if (n < NN) {
        float v = x[n * DIN + lane];
        float av = fabsf(v);
#pragma unroll
        for (int s = 32; s; s >>= 1) av = fmaxf(av, __shfl_xor(av, s));
        const float inv = (av > 0.f) ? 127.f / av : 0.f;
        xq[n * DIN + lane] = (signed char)(int)rintf(v * inv);
        if (lane == 0) xs[n] = av * (1.f / 127.f);
    }
}

// all 3 layers' comp [R,30] fp32 -> padded f32 [3][R,32]
__global__ void k_prep_comp3(const float* __restrict__ c0, const float* __restrict__ c1,
                             const float* __restrict__ c2, float* __restrict__ cp) {
    int idx = blockIdx.x * 256 + threadIdx.x;
    if (idx < 3 * RR * CPAD) {
        int l = idx / (RR * CPAD);
        int rem = idx - l * (RR * CPAD);
        int r = rem / CPAD, i = rem - r * CPAD;
        const float* c = (l == 0) ? c0 : (l == 1) ? c1 : c2;
        cp[idx] = (i < BB) ? c[r * BB + i] : 0.f;
    }
}

// all 3 layers' transposed bf16 weights
__global__ void k_prep_w3(const float* __restrict__ b0, const float* __restrict__ r0,
                          const float* __restrict__ b1, const float* __restrict__ r1,
                          const float* __restrict__ b2, const float* __restrict__ r2,
                          short* __restrict__ wt) {
    int idx = blockIdx.x * 256 + threadIdx.x;
    if (idx >= 144 * KTOT) return;
    int row = idx / KTOT, k = idx - row * KTOT;
    const float* bs; const float* rt; int o, dout;
    if (row < 64)       { bs = b0; rt = r0; o = row;        dout = 64; }
    else if (row < 128) { bs = b1; rt = r1; o = row - 64;   dout = 64; }
    else                { bs = b2; rt = r2; o = row - 128;  dout = 8;  }
    float v = 0.f;
    if (o < dout)
        v = (k < BB * DIN) ? bs[k * dout + o] : rt[(k - BB * DIN) * dout + o];
    __hip_bfloat16 hb = __float2bfloat16(v);
    wt[idx] = *reinterpret_cast<const short*>(&hb);
}

// ---------------- fused per-layer kernel ----------------
// FETCH-BOUND MODEL (R0-R7: dur == (FETCH+WRITE)/~400 GB/s for every schedule).
// Byte attack, accuracy-safe version of R8:
//  * activations int8 [N][64] (3.2 MB < 4 MB per-XCD L2) + per-node f32 row
//    scale (200 KB). Quantization error ~0.4% of row max (vs e4m3's 6.25%
//    that failed absmax in R8).
//  * 4-byte records (src|rel|cnt); a = scale[src]/cnt via LDS rcp LUT
//    (rcp[0]=0 -> ghost edges exact no-ops).
//  * f32 accumulation; t_tile/MFMA bf16 (same as passing baseline).
// Structure as R7/R8: 1024 thr / 16 waves / 2 blocks/CU, 8-edge iterations,
// records SMEM 2 ahead, gathers 1 iteration ahead, degree-sorted nodes.
// RELU layers emit int8+scale (rowmax via LDS atomicMax, +1 barrier).

#define LOADR8(u, RA, RB) do {                                                  \
    const int _u = ((u) < nit) ? (u) : (nit - 1);                               \
    RA = rec4[2 * _u]; RB = rec4[2 * _u + 1];                                   \
} while (0)

#define GATH1(sx) ((int)xss[((sx) & 0xFFFF) * DIN + lane])

// one edge: comp row (8x s_load dwordx4) + rcp LUT + scale + 32 FMAs (f32 acc)
#define EDGE_FMA1(_sx, _gi) do {                                                \
    const int _c = ((_sx) >> 22) & 255;                                         \
    const float _sc = xscale[(_sx) & 0xFFFF];                                   \
    const float _a = _sc * rcpl[_c];                                            \
    const floatx4* _q = (const floatx4*)(compP + (((_sx) >> 16) & 63) * CPAD);  \
    const float _xv = (float)(_gi) * _a;                                        \
    const floatx4 _w = {_xv, _xv, _xv, _xv};                                    \
    acc[0] = _q[0] * _w + acc[0];  acc[1] = _q[1] * _w + acc[1];                \
    acc[2] = _q[2] * _w + acc[2];  acc[3] = _q[3] * _w + acc[3];                \
    acc[4] = _q[4] * _w + acc[4];  acc[5] = _q[5] * _w + acc[5];                \
    acc[6] = _q[6] * _w + acc[6];  acc[7] = _q[7] * _w + acc[7];                \
} while (0)

template <int DOUT, bool RELU>
__global__ __launch_bounds__(1024, 8)
void k_fused(const signed char* __restrict__ xss,    // [N][64] int8
             const float* __restrict__ xscale,       // [N] row scale
             const int* __restrict__ ep,
             const int* __restrict__ doff, const int* __restrict__ dcount,
             const int* __restrict__ order,
             const float* __restrict__ compP,    // [R, 32] f32 padded
             const short* __restrict__ Wt,       // [DPAD][KTOT] bf16 (transposed)
             const float* __restrict__ bias,     // [DOUT]
             void* __restrict__ outp,            // RELU: int8 [N][64]; else f32 [N][8]
             float* __restrict__ oscale) {       // RELU: [N] out row scale
    __shared__ __align__(16) char smem_raw[NBW * ROWE * 2];   // 63744 B
    __shared__ float rcpl[256];                               // 1/c LUT, rcp[0]=0
    auto t_tile = reinterpret_cast<__hip_bfloat16(*)[ROWE]>(smem_raw);
    const int tid  = threadIdx.x;
    const int lane = tid & 63;
    const int wv   = RFL(tid >> 6);          // 0..15
    const int node0 = blockIdx.x * NBW;

    if (tid < 256) rcpl[tid] = (tid == 0) ? 0.f : (1.0f / (float)tid);

    const int n   = RFL(order[node0 + wv]);
    const int beg = RFL(doff[n]);            // multiple of 8
    const int nit = RFL(dcount[n]) >> 3;     // 8-edge iterations
    const int selfq = GATH1(n);              // self row int8 (issued early)
    const float sscale = RFL(__float_as_int(xscale[n])) == 0 ? 0.f : xscale[n]; // uniform load

    __syncthreads();                          // rcpl ready for all waves

    // ---- phase 1: one node per wave, 8-edge pipelined iterations ----
    {
        floatx4 acc[8];
#pragma unroll
        for (int u = 0; u < 8; ++u) acc[u] = (floatx4){0.f, 0.f, 0.f, 0.f};

        if (nit > 0) {
            const int4* rec4 = (const int4*)(ep + beg);   // uniform -> s_load
            int4 A0, A1, B0, B1, C0, C1;
            LOADR8(0, A0, A1);
            LOADR8(1, B0, B1);
            // gathers for chunk 0 (records in A)
            int g0 = GATH1(RFL(A0.x)), g1 = GATH1(RFL(A0.y));
            int g2 = GATH1(RFL(A0.z)), g3 = GATH1(RFL(A0.w));
            int g4 = GATH1(RFL(A1.x)), g5 = GATH1(RFL(A1.y));
            int g6 = GATH1(RFL(A1.z)), g7 = GATH1(RFL(A1.w));

            for (int t = 0; t < nit; ++t) {
                // gathers for chunk t+1 (records in B, arrived)
                int h0 = GATH1(RFL(B0.x)), h1 = GATH1(RFL(B0.y));
                int h2 = GATH1(RFL(B0.z)), h3 = GATH1(RFL(B0.w));
                int h4 = GATH1(RFL(B1.x)), h5 = GATH1(RFL(B1.y));
                int h6 = GATH1(RFL(B1.z)), h7 = GATH1(RFL(B1.w));
                // 8 edges of chunk t
                EDGE_FMA1(RFL(A0.x), g0); EDGE_FMA1(RFL(A0.y), g1);
                EDGE_FMA1(RFL(A0.z), g2); EDGE_FMA1(RFL(A0.w), g3);
                EDGE_FMA1(RFL(A1.x), g4); EDGE_FMA1(RFL(A1.y), g5);
                EDGE_FMA1(RFL(A1.z), g6); EDGE_FMA1(RFL(A1.w), g7);
                // records for chunk t+2, issued after all comp consumes
                __builtin_amdgcn_sched_barrier(0);
                LOADR8(t + 2, C0, C1);
                A0 = B0; A1 = B1; B0 = C0; B1 = C1;
                g0 = h0; g1 = h1; g2 = h2; g3 = h3;
                g4 = h4; g5 = h5; g6 = h6; g7 = h7;
            }
        }
#pragma unroll
        for (int b = 0; b < BB; ++b)
            t_tile[wv][b * DIN + lane] = __float2bfloat16(acc[b >> 2][b & 3]);
        t_tile[wv][BB * DIN + lane] = __float2bfloat16((float)selfq * sscale);
    }
    __syncthreads();

    // ---- phase 2: MFMA 16x16x32 bf16, K = 1984 (62 steps) over 16 waves ----
    const int m = lane & 15;
    const int q = lane >> 4;
    int kk0, nsteps, col_base, kpart;
    if (DOUT == 64) {
        kpart = wv >> 2;                 // 0..3
        col_base = (wv & 3) * 16;
        kk0    = (kpart <= 1) ? kpart * 16 : (kpart == 2 ? 32 : 47);
        nsteps = (kpart <= 1) ? 16 : 15;
    } else {
        kpart = wv;                      // 0..15
        col_base = 0;
        kk0    = (kpart < 14) ? kpart * 4 : (kpart == 14 ? 56 : 59);
        nsteps = (kpart < 14) ? 4 : 3;
    }
    const __hip_bfloat16* arow = &t_tile[m][q * 8];
    const short* brow = Wt + (size_t)(col_base + m) * KTOT + q * 8;

    floatx4 acc0 = {0.f, 0.f, 0.f, 0.f};
    floatx4 acc1 = {0.f, 0.f, 0.f, 0.f};
    int s = 0;
    for (; s + 2 <= nsteps; s += 2) {
        const int kk = kk0 + s;
        short8 a0 = *reinterpret_cast<const short8*>(arow + kk * 32);
        short8 b0 = *reinterpret_cast<const short8*>(brow + kk * 32);
        short8 a1 = *reinterpret_cast<const short8*>(arow + (kk + 1) * 32);
        short8 b1 = *reinterpret_cast<const short8*>(brow + (kk + 1) * 32);
        acc0 = __builtin_amdgcn_mfma_f32_16x16x32_bf16(a0, b0, acc0, 0, 0, 0);
        acc1 = __builtin_amdgcn_mfma_f32_16x16x32_bf16(a1, b1, acc1, 0, 0, 0);
    }
    if (s < nsteps) {
        const int kk = kk0 + s;
        short8 a0 = *reinterpret_cast<const short8*>(arow + kk * 32);
        short8 b0 = *reinterpret_cast<const short8*>(brow + kk * 32);
        acc0 = __builtin_amdgcn_mfma_f32_16x16x32_bf16(a0, b0, acc0, 0, 0, 0);
    }
    floatx4 P = acc0 + acc1;

    __syncthreads();                       // all t_tile reads done
    float* red = (float*)smem_raw;         // reuse LDS; stride-6 layout
    float* rowmax = (float*)(smem_raw + 20480);   // 16 floats, past red slots

    if (DOUT == 64) {
        if (kpart > 0) {
            const int slot = (wv & 3) * 3 + (kpart - 1);   // 0..11
            const int off = (slot * 64 + lane) * 6;
            red[off] = P[0]; red[off + 1] = P[1]; red[off + 2] = P[2]; red[off + 3] = P[3];
        }
        if (tid < 16) ((int*)rowmax)[tid] = 0;
        __syncthreads();
        float vr[4];
        if (kpart == 0) {
#pragma unroll
            for (int t = 0; t < 3; ++t) {
                const int off = (((wv & 3) * 3 + t) * 64 + lane) * 6;
                P[0] += red[off]; P[1] += red[off + 1];
                P[2] += red[off + 2]; P[3] += red[off + 3];
            }
            const int o = col_base + m;
            const float bi = bias[o];
#pragma unroll
            for (int r = 0; r < 4; ++r) {
                const float v = fmaxf(P[r] + bi, 0.f);   // ReLU, v >= 0
                vr[r] = v;
                atomicMax((int*)&rowmax[q * 4 + r], __float_as_int(v));
            }
        }
        __syncthreads();
        if (kpart == 0) {
            const int o = col_base + m;
#pragma unroll
            for (int r = 0; r < 4; ++r) {
                const int slot2 = q * 4 + r;
                const float mx = rowmax[slot2];
                const float inv = (mx > 0.f) ? 127.f / mx : 0.f;
                const int nw = order[node0 + slot2];
                reinterpret_cast<signed char*>(outp)[(size_t)nw * 64 + o] =
                    (signed char)(int)rintf(vr[r] * inv);
                if (wv == 0 && m == 0) oscale[nw] = mx * (1.f / 127.f);
            }
        }
    } else {
        if (kpart > 0) {
            const int off = ((kpart - 1) * 64 + lane) * 6;
            red[off] = P[0]; red[off + 1] = P[1]; red[off + 2] = P[2]; red[off + 3] = P[3];
        }
        __syncthreads();
        if (kpart == 0) {
#pragma unroll
            for (int w = 0; w < 15; ++w) {
                const int off = (w * 64 + lane) * 6;
                P[0] += red[off]; P[1] += red[off + 1];
                P[2] += red[off + 2]; P[3] += red[off + 3];
            }
            if (m < DOUT) {
                const int o = m;
                const float bi = bias[o];
#pragma unroll
                for (int r = 0; r < 4; ++r) {
                    const int nw = order[node0 + q * 4 + r];
                    reinterpret_cast<float*>(outp)[(size_t)nw * DOUT + o] = P[r] + bi;
                }
            }
        }
    }
}

// ---------------- log_softmax over C=8 ----------------
__global__ void k_lsm(const float* __restrict__ pre, float* __restrict__ out) {
    int n = blockIdx.x * 256 + threadIdx.x;
    if (n < NN) {
        float v[8];
        float mx = -1e30f;
#pragma unroll
        for (int c = 0; c < 8; ++c) { v[c] = pre[n * 8 + c]; mx = fmaxf(mx, v[c]); }
        float s = 0.f;
#pragma unroll
        for (int c = 0; c < 8; ++c) s += expf(v[c] - mx);
        float ls = logf(s);
#pragma unroll
        for (int c = 0; c < 8; ++c) out[n * 8 + c] = v[c] - mx - ls;
    }
}

// ---------------- launch ----------------
extern "C" void kernel_launch(void* const* d_in, const int* in_sizes, int n_in,
                              void* d_out, int out_size, void* d_ws, size_t ws_size,
                              hipStream_t stream) {
    const float* x     = (const float*)d_in[0];
    const int*   eidx  = (const int*)d_in[1];
    const int*   etype = (const int*)d_in[2];
    const float* bases0 = (const float*)d_in[3];
    const float* comp0  = (const float*)d_in[4];
    const float* root0  = (const float*)d_in[5];
    const float* bias0  = (const float*)d_in[6];
    const float* bases1 = (const float*)d_in[7];
    const float* comp1  = (const float*)d_in[8];
    const float* root1  = (const float*)d_in[9];
    const float* bias1  = (const float*)d_in[10];
    const float* bases2 = (const float*)d_in[11];
    const float* comp2  = (const float*)d_in[12];
    const float* root2  = (const float*)d_in[13];
    const float* bias2  = (const float*)d_in[14];
    const int* srcp = eidx;
    const int* dstp = eidx + EE;

    char* p = (char*)d_ws;
    auto carve = [&](size_t bytes) -> char* {
        char* r = p;
        p += (bytes + 255) & ~(size_t)255;
        return r;
    };
    int*  cnt    = (int*)carve((size_t)NN * RR * sizeof(int));   // 10 MB
    int*  dcount = (int*)carve((size_t)NN * sizeof(int));
    int*  cursor = (int*)carve((size_t)NN * sizeof(int));
    int*  doff   = (int*)carve((size_t)NN * sizeof(int));
    int*  bsum   = (int*)carve(256 * sizeof(int));
    int*  dbin   = (int*)carve(256 * sizeof(int));
    int*  dcur   = (int*)carve(256 * sizeof(int));
    int*  order  = (int*)carve((size_t)NN * sizeof(int));
    int*  ep     = (int*)carve((size_t)EPAD * sizeof(int));      // ~4.7 MB
    signed char* xqA = (signed char*)carve((size_t)NN * DIN);    // 3.2 MB
    signed char* xqB = (signed char*)carve((size_t)NN * DIN);    // 3.2 MB
    float* xsA = (float*)carve((size_t)NN * sizeof(float));      // 200 KB
    float* xsB = (float*)carve((size_t)NN * sizeof(float));
    float* pre = (float*)carve((size_t)NN * 8 * sizeof(float));
    short* wtA = (short*)carve((size_t)144 * KTOT * sizeof(short));
    float* cpA = (float*)carve((size_t)3 * RR * CPAD * sizeof(float));

    // cnt, dcount, cursor adjacent -> one memset
    hipMemsetAsync(cnt, 0, (size_t)NN * (RR + 2) * sizeof(int) + 512, stream);
    hipMemsetAsync(dbin, 0, 2048, stream);
    // ghost record slots must be zero (cnt=0 -> a=0 -> exact no-op edges)
    hipMemsetAsync(ep, 0, (size_t)EPAD * sizeof(int), stream);

    const int EB = (EE + 255) / 256;   // 3907
    const int NB = (NN + 255) / 256;   // 196
    k_hist<<<EB, 256, 0, stream>>>(dstp, etype, cnt);
    k_scan1<<<NB, 256, 0, stream>>>(cnt, dcount, doff, bsum);
    k_scan2<<<1, 256, 0, stream>>>(bsum, NB);
    k_scan3<<<NB, 256, 0, stream>>>(doff, bsum);
    k_scatter<<<EB, 256, 0, stream>>>(srcp, dstp, etype, cnt, doff, cursor, ep);
    k_deghist<<<NB, 256, 0, stream>>>(dcount, dbin);
    k_degscan<<<1, 256, 0, stream>>>(dbin);
    k_degscatter<<<NB, 256, 0, stream>>>(dcount, dbin, dcur, order);
    k_quant_x<<<(NN + 3) / 4, 256, 0, stream>>>(x, xqA, xsA);
    k_prep_comp3<<<(3 * RR * CPAD + 255) / 256, 256, 0, stream>>>(comp0, comp1, comp2, cpA);
    k_prep_w3<<<(144 * KTOT + 255) / 256, 256, 0, stream>>>(bases0, root0, bases1, root1,
                                                            bases2, root2, wtA);

    short* wt0 = wtA;
    short* wt1 = wtA + (size_t)64 * KTOT;
    short* wt2 = wtA + (size_t)128 * KTOT;
    float* cp0 = cpA;
    float* cp1 = cpA + RR * CPAD;
    float* cp2 = cpA + 2 * RR * CPAD;

    const int NF = NN / NBW;   // 3125 (exact)
    k_fused<64, true ><<<NF, 1024, 0, stream>>>(xqA, xsA, ep, doff, dcount, order,
                                                cp0, wt0, bias0, (void*)xqB, xsB);
    k_fused<64, true ><<<NF, 1024, 0, stream>>>(xqB, xsB, ep, doff, dcount, order,
                                                cp1, wt1, bias1, (void*)xqA, xsA);
    k_fused<8,  false><<<NF, 1024, 0, stream>>>(xqA, xsA, ep, doff, dcount, order,
                                                cp2, wt2, bias2, (void*)pre, xsB);
    k_lsm<<<NB, 256, 0, stream>>>(pre, (float*)d_out);
}

// Round 10
// 594.977 us; speedup vs baseline: 1.0348x; 1.0348x over previous
//
#include <hip/hip_runtime.h>
#include <hip/hip_bf16.h>
#include <hip/hip_fp16.h>
#include <stdint.h>

// Problem constants (fixed by the reference)
#define NN   50000
#define RR   50
#define BB   30
#define DIN  64
#define EE   1000000
#define KTOT (BB*DIN + DIN)   // 1984 = 62*32
#define NBW  16               // nodes per workgroup; 50000 = 3125*16 exactly
#define ROWE (KTOT + 8)       // padded LDS row: 1992 elems (3984 B)
#define CPAD 32               // comp row padded 30 -> 32 halves (64 B)
#define EPAD (EE + 8*NN + 32) // ep2 entries incl. per-node 8-alignment ghosts

typedef __attribute__((ext_vector_type(8))) short short8;
typedef __attribute__((ext_vector_type(4))) float floatx4;

#define RFL(x) __builtin_amdgcn_readfirstlane(x)

// ---------------- preprocessing: counting sort of edges by dst ----------------

__global__ void k_hist(const int* __restrict__ dst, const int* __restrict__ et,
                       int* __restrict__ cnt) {
    int e = blockIdx.x * 256 + threadIdx.x;
    if (e < EE) {
        int d = dst[e], r = et[e];
        atomicAdd(&cnt[d * RR + r], 1);
    }
}

// derive dcount from cnt rows; PAD each node's segment to a multiple of 8
__global__ void k_scan1(const int* __restrict__ cnt, int* __restrict__ dcount,
                        int* __restrict__ doff, int* __restrict__ bsum) {
    __shared__ int sh[256];
    int t = threadIdx.x;
    int i = blockIdx.x * 256 + t;
    int vp = 0;
    if (i < NN) {
        const int* c = cnt + (size_t)i * RR;
        int v = 0;
#pragma unroll
        for (int r = 0; r < RR; ++r) v += c[r];
        vp = (v + 7) & ~7;
        dcount[i] = vp;
    }
    sh[t] = vp;
    __syncthreads();
    for (int s = 1; s < 256; s <<= 1) {
        int add = (t >= s) ? sh[t - s] : 0;
        __syncthreads();
        sh[t] += add;
        __syncthreads();
    }
    int incl = sh[t];
    if (i < NN) doff[i] = incl - vp;
    if (t == 255) bsum[blockIdx.x] = incl;
}

__global__ void k_scan2(int* __restrict__ bsum, int nbv) {
    __shared__ int sh[256];
    int t = threadIdx.x;
    int v = (t < nbv) ? bsum[t] : 0;
    sh[t] = v;
    __syncthreads();
    for (int s = 1; s < 256; s <<= 1) {
        int add = (t >= s) ? sh[t - s] : 0;
        __syncthreads();
        sh[t] += add;
        __syncthreads();
    }
    if (t < nbv) bsum[t] = sh[t] - v;
}

__global__ void k_scan3(int* __restrict__ doff, const int* __restrict__ bsum) {
    int i = blockIdx.x * 256 + threadIdx.x;
    if (i < NN) doff[i] += bsum[blockIdx.x];
}

// records: .x = src | (rel<<16)  (src<65536, rel<50), .y = bits of a = 1/cnt(d,r)
__global__ void k_scatter(const int* __restrict__ src, const int* __restrict__ dst,
                          const int* __restrict__ et, const int* __restrict__ cnt,
                          const int* __restrict__ doff, int* __restrict__ cursor,
                          int2* __restrict__ ep2) {
    int e = blockIdx.x * 256 + threadIdx.x;
    if (e < EE) {
        int d = dst[e], r = et[e], s = src[e];
        int p = doff[d] + atomicAdd(&cursor[d], 1);
        float a = 1.0f / (float)cnt[d * RR + r];
        ep2[p] = make_int2(s | (r << 16), __float_as_int(a));
    }
}

// ---------------- degree counting-sort (descending) for wave balance ----------
// LDS-aggregated two-level histograms (<=256 global atomics per block).

__global__ void k_deghist(const int* __restrict__ dcount, int* __restrict__ dbin) {
    __shared__ int lh[256];
    int t = threadIdx.x;
    int i = blockIdx.x * 256 + t;
    lh[t] = 0;
    __syncthreads();
    if (i < NN) {
        int d = dcount[i]; d = (d > 255) ? 255 : d;
        atomicAdd(&lh[255 - d], 1);
    }
    __syncthreads();
    if (lh[t]) atomicAdd(&dbin[t], lh[t]);
}

__global__ void k_degscan(int* __restrict__ dbin) {
    __shared__ int sh[256];
    int t = threadIdx.x;
    int v = dbin[t];
    sh[t] = v;
    __syncthreads();
    for (int s = 1; s < 256; s <<= 1) {
        int add = (t >= s) ? sh[t - s] : 0;
        __syncthreads();
        sh[t] += add;
        __syncthreads();
    }
    dbin[t] = sh[t] - v;
}

__global__ void k_degscatter(const int* __restrict__ dcount, const int* __restrict__ dbin,
                             int* __restrict__ dcur, int* __restrict__ order) {
    __shared__ int lh[256], lbase[256];
    int t = threadIdx.x;
    int i = blockIdx.x * 256 + t;
    lh[t] = 0;
    __syncthreads();
    int b = 0, lpos = 0;
    if (i < NN) {
        int d = dcount[i]; d = (d > 255) ? 255 : d;
        b = 255 - d;
        lpos = atomicAdd(&lh[b], 1);
    }
    __syncthreads();
    lbase[t] = lh[t] ? atomicAdd(&dcur[t], lh[t]) : 0;
    __syncthreads();
    if (i < NN) order[dbin[b] + lbase[b] + lpos] = i;
}

__global__ void k_cast_x(const float* __restrict__ x, __hip_bfloat16* __restrict__ h) {
    int i = blockIdx.x * 256 + threadIdx.x;     // processes 4 elems
    if (i < NN * DIN / 4) {
        float4 v = reinterpret_cast<const float4*>(x)[i];
        ushort4 o;
        o.x = (ushort)(__bfloat16_as_ushort(__float2bfloat16(v.x)));
        o.y = (ushort)(__bfloat16_as_ushort(__float2bfloat16(v.y)));
        o.z = (ushort)(__bfloat16_as_ushort(__float2bfloat16(v.z)));
        o.w = (ushort)(__bfloat16_as_ushort(__float2bfloat16(v.w)));
        reinterpret_cast<ushort4*>(h)[i] = o;
    }
}

// all 3 layers' comp [R,30] fp32 -> padded f16 [3][R,32]
__global__ void k_prep_comp3(const float* __restrict__ c0, const float* __restrict__ c1,
                             const float* __restrict__ c2, __half* __restrict__ cp) {
    int idx = blockIdx.x * 256 + threadIdx.x;
    if (idx < 3 * RR * CPAD) {
        int l = idx / (RR * CPAD);
        int rem = idx - l * (RR * CPAD);
        int r = rem / CPAD, i = rem - r * CPAD;
        const float* c = (l == 0) ? c0 : (l == 1) ? c1 : c2;
        cp[idx] = (i < BB) ? __float2half(c[r * BB + i]) : __float2half(0.f);
    }
}

// all 3 layers' transposed bf16 weights
__global__ void k_prep_w3(const float* __restrict__ b0, const float* __restrict__ r0,
                          const float* __restrict__ b1, const float* __restrict__ r1,
                          const float* __restrict__ b2, const float* __restrict__ r2,
                          short* __restrict__ wt) {
    int idx = blockIdx.x * 256 + threadIdx.x;
    if (idx >= 144 * KTOT) return;
    int row = idx / KTOT, k = idx - row * KTOT;
    const float* bs; const float* rt; int o, dout;
    if (row < 64)       { bs = b0; rt = r0; o = row;        dout = 64; }
    else if (row < 128) { bs = b1; rt = r1; o = row - 64;   dout = 64; }
    else                { bs = b2; rt = r2; o = row - 128;  dout = 8;  }
    float v = 0.f;
    if (o < dout)
        v = (k < BB * DIN) ? bs[k * dout + o] : rt[(k - BB * DIN) * dout + o];
    __hip_bfloat16 hb = __float2bfloat16(v);
    wt[idx] = *reinterpret_cast<const short*>(&hb);
}

// ---------------- fused per-layer kernel ----------------
// SCALAR-PIPE MODEL (R9 falsified fetch-bound: bytes halved, time UP 20%;
// what R9 added was per-edge SCALAR work). Every 140-150us variant shared
// ~10-15 scalar-pipe ops/edge (8x s_load_dwordx4 comp + addressing) on the
// CU's single scalar unit, shared by 32 waves, with out-of-order SMEM forcing
// lgkmcnt(0) drains per edge. This version moves comp to LDS:
//  * comp f16 [50][32] in LDS (3.2 KB), read per edge as 4x wave-uniform
//    ds_read_b128 (broadcast, conflict-free, IN-ORDER -> counted lgkm waits).
//  * per-edge scalar cost drops to ~2 ops (amortized record s_loads).
//  * everything else = proven R5/R7 hybrid: bf16 activations, f16 hfma2 acc
//    (absmax 1.5 proven in R7), 8-edge iterations, records SMEM 2 ahead
//    (3-stage SGPR rotation + sched_barrier), gathers 1 ahead, degree sort.
// Phase 2 unchanged: MFMA 16x16x32 bf16 over K=1984.

#define LOADR8(u, R0, R1, R2, R3) do {                                          \
    const int _u = ((u) < nit) ? (u) : (nit - 1);                               \
    R0 = rec4[4 * _u];     R1 = rec4[4 * _u + 1];                               \
    R2 = rec4[4 * _u + 2]; R3 = rec4[4 * _u + 3];                               \
} while (0)

#define GATH1(sx) ((unsigned)xin16[((sx) & 0xFFFF) * DIN + lane])

// one edge: comp row from LDS (4x ds_read_b128 broadcast) + 16 hfma2, f16 acc
#define EDGE_FMA1(_sx, _ai, _g) do {                                            \
    const int4* _cr = (const int4*)(compL + (((unsigned)(_sx)) >> 16) * CPAD);  \
    int4 _m0 = _cr[0], _m1 = _cr[1], _m2 = _cr[2], _m3 = _cr[3];                \
    const float _xvf = __uint_as_float((unsigned)(_g) << 16) * __int_as_float(_ai); \
    const __half _xh = __float2half(_xvf);                                      \
    const __half2 _xv2 = __halves2half2(_xh, _xh);                              \
    const __half2* _p0 = reinterpret_cast<const __half2*>(&_m0);                \
    const __half2* _p1 = reinterpret_cast<const __half2*>(&_m1);                \
    const __half2* _p2 = reinterpret_cast<const __half2*>(&_m2);                \
    const __half2* _p3 = reinterpret_cast<const __half2*>(&_m3);                \
    acc[0]  = __hfma2(_p0[0], _xv2, acc[0]);                                    \
    acc[1]  = __hfma2(_p0[1], _xv2, acc[1]);                                    \
    acc[2]  = __hfma2(_p0[2], _xv2, acc[2]);                                    \
    acc[3]  = __hfma2(_p0[3], _xv2, acc[3]);                                    \
    acc[4]  = __hfma2(_p1[0], _xv2, acc[4]);                                    \
    acc[5]  = __hfma2(_p1[1], _xv2, acc[5]);                                    \
    acc[6]  = __hfma2(_p1[2], _xv2, acc[6]);                                    \
    acc[7]  = __hfma2(_p1[3], _xv2, acc[7]);                                    \
    acc[8]  = __hfma2(_p2[0], _xv2, acc[8]);                                    \
    acc[9]  = __hfma2(_p2[1], _xv2, acc[9]);                                    \
    acc[10] = __hfma2(_p2[2], _xv2, acc[10]);                                   \
    acc[11] = __hfma2(_p2[3], _xv2, acc[11]);                                   \
    acc[12] = __hfma2(_p3[0], _xv2, acc[12]);                                   \
    acc[13] = __hfma2(_p3[1], _xv2, acc[13]);                                   \
    acc[14] = __hfma2(_p3[2], _xv2, acc[14]);                                   \
    acc[15] = __hfma2(_p3[3], _xv2, acc[15]);                                   \
} while (0)

template <int DOUT, bool RELU>
__global__ __launch_bounds__(1024, 8)
void k_fused(const __hip_bfloat16* __restrict__ xin,
             const int2* __restrict__ ep2,
             const int* __restrict__ doff, const int* __restrict__ dcount,
             const int* __restrict__ order,
             const __half* __restrict__ compH,   // [R, 32] f16 padded (global)
             const short* __restrict__ Wt,       // [DPAD][KTOT] bf16 (transposed)
             const float* __restrict__ bias,     // [DOUT]
             void* __restrict__ outp) {
    __shared__ __align__(16) char smem_raw[NBW * ROWE * 2];   // 63744 B
    __shared__ __align__(16) __half compL[RR * CPAD];          // 3200 B
    auto t_tile = reinterpret_cast<__hip_bfloat16(*)[ROWE]>(smem_raw);
    const unsigned short* xin16 = reinterpret_cast<const unsigned short*>(xin);
    const int tid  = threadIdx.x;
    const int lane = tid & 63;
    const int wv   = RFL(tid >> 6);          // 0..15
    const int node0 = blockIdx.x * NBW;

    // stage comp into LDS (one pass; 1600 halves over 1024 threads)
    if (tid < RR * CPAD / 2)
        reinterpret_cast<__half2*>(compL)[tid] =
            reinterpret_cast<const __half2*>(compH)[tid];

    const int n   = RFL(order[node0 + wv]);
    const int beg = RFL(doff[n]);            // multiple of 8
    const int nit = RFL(dcount[n]) >> 3;     // 8-edge iterations
    const unsigned selfb = GATH1(n);         // self row (issued early)

    __syncthreads();                          // compL ready

    // ---- phase 1: one node per wave, 8-edge pipelined iterations ----
    {
        __half2 acc[16];
#pragma unroll
        for (int u = 0; u < 16; ++u)
            acc[u] = __halves2half2(__float2half(0.f), __float2half(0.f));

        if (nit > 0) {
            const int4* rec4 = (const int4*)(ep2 + beg);   // uniform -> s_load
            // 3-stage record rotation: A = chunk t, B = chunk t+1, C = loading t+2
            int4 A0, A1, A2, A3, B0, B1, B2, B3, C0, C1, C2, C3;
            LOADR8(0, A0, A1, A2, A3);
            LOADR8(1, B0, B1, B2, B3);
            // gathers for chunk 0 (records in A)
            unsigned g0 = GATH1(RFL(A0.x)), g1 = GATH1(RFL(A0.z));
            unsigned g2 = GATH1(RFL(A1.x)), g3 = GATH1(RFL(A1.z));
            unsigned g4 = GATH1(RFL(A2.x)), g5 = GATH1(RFL(A2.z));
            unsigned g6 = GATH1(RFL(A3.x)), g7 = GATH1(RFL(A3.z));

            for (int t = 0; t < nit; ++t) {
                // gathers for chunk t+1 (records in B, arrived)
                unsigned h0 = GATH1(RFL(B0.x)), h1 = GATH1(RFL(B0.z));
                unsigned h2 = GATH1(RFL(B1.x)), h3 = GATH1(RFL(B1.z));
                unsigned h4 = GATH1(RFL(B2.x)), h5 = GATH1(RFL(B2.z));
                unsigned h6 = GATH1(RFL(B3.x)), h7 = GATH1(RFL(B3.z));
                // 8 edges of chunk t (comp from LDS, in-order counted waits)
                EDGE_FMA1(RFL(A0.x), RFL(A0.y), g0);
                EDGE_FMA1(RFL(A0.z), RFL(A0.w), g1);
                EDGE_FMA1(RFL(A1.x), RFL(A1.y), g2);
                EDGE_FMA1(RFL(A1.z), RFL(A1.w), g3);
                EDGE_FMA1(RFL(A2.x), RFL(A2.y), g4);
                EDGE_FMA1(RFL(A2.z), RFL(A2.w), g5);
                EDGE_FMA1(RFL(A3.x), RFL(A3.y), g6);
                EDGE_FMA1(RFL(A3.z), RFL(A3.w), g7);
                // records for chunk t+2, issued after all comp consumes
                __builtin_amdgcn_sched_barrier(0);
                LOADR8(t + 2, C0, C1, C2, C3);
                A0 = B0; A1 = B1; A2 = B2; A3 = B3;
                B0 = C0; B1 = C1; B2 = C2; B3 = C3;
                g0 = h0; g1 = h1; g2 = h2; g3 = h3;
                g4 = h4; g5 = h5; g6 = h6; g7 = h7;
            }
        }
#pragma unroll
        for (int b = 0; b < BB; ++b) {
            const float v = (b & 1) ? __high2float(acc[b >> 1]) : __low2float(acc[b >> 1]);
            t_tile[wv][b * DIN + lane] = __float2bfloat16(v);
        }
        t_tile[wv][BB * DIN + lane] =
            __float2bfloat16(__uint_as_float(selfb << 16));
    }
    __syncthreads();

    // ---- phase 2: MFMA 16x16x32 bf16, K = 1984 (62 steps) over 16 waves ----
    const int m = lane & 15;
    const int q = lane >> 4;
    int kk0, nsteps, col_base, kpart;
    if (DOUT == 64) {
        kpart = wv >> 2;                 // 0..3
        col_base = (wv & 3) * 16;
        kk0    = (kpart <= 1) ? kpart * 16 : (kpart == 2 ? 32 : 47);
        nsteps = (kpart <= 1) ? 16 : 15;
    } else {
        kpart = wv;                      // 0..15
        col_base = 0;
        kk0    = (kpart < 14) ? kpart * 4 : (kpart == 14 ? 56 : 59);
        nsteps = (kpart < 14) ? 4 : 3;
    }
    const __hip_bfloat16* arow = &t_tile[m][q * 8];
    const short* brow = Wt + (size_t)(col_base + m) * KTOT + q * 8;

    floatx4 acc0 = {0.f, 0.f, 0.f, 0.f};
    floatx4 acc1 = {0.f, 0.f, 0.f, 0.f};
    int s = 0;
    for (; s + 2 <= nsteps; s += 2) {
        const int kk = kk0 + s;
        short8 a0 = *reinterpret_cast<const short8*>(arow + kk * 32);
        short8 b0 = *reinterpret_cast<const short8*>(brow + kk * 32);
        short8 a1 = *reinterpret_cast<const short8*>(arow + (kk + 1) * 32);
        short8 b1 = *reinterpret_cast<const short8*>(brow + (kk + 1) * 32);
        acc0 = __builtin_amdgcn_mfma_f32_16x16x32_bf16(a0, b0, acc0, 0, 0, 0);
        acc1 = __builtin_amdgcn_mfma_f32_16x16x32_bf16(a1, b1, acc1, 0, 0, 0);
    }
    if (s < nsteps) {
        const int kk = kk0 + s;
        short8 a0 = *reinterpret_cast<const short8*>(arow + kk * 32);
        short8 b0 = *reinterpret_cast<const short8*>(brow + kk * 32);
        acc0 = __builtin_amdgcn_mfma_f32_16x16x32_bf16(a0, b0, acc0, 0, 0, 0);
    }
    floatx4 P = acc0 + acc1;

    __syncthreads();                       // all t_tile reads done
    float* red = (float*)smem_raw;         // reuse LDS; stride-6 layout

    if (DOUT == 64) {
        if (kpart > 0) {
            const int slot = (wv & 3) * 3 + (kpart - 1);   // 0..11
            const int off = (slot * 64 + lane) * 6;
            red[off] = P[0]; red[off + 1] = P[1]; red[off + 2] = P[2]; red[off + 3] = P[3];
        }
        __syncthreads();
        if (kpart == 0) {
#pragma unroll
            for (int t = 0; t < 3; ++t) {
                const int off = (((wv & 3) * 3 + t) * 64 + lane) * 6;
                P[0] += red[off]; P[1] += red[off + 1];
                P[2] += red[off + 2]; P[3] += red[off + 3];
            }
            const int o = col_base + m;
            const float bi = bias[o];
#pragma unroll
            for (int r = 0; r < 4; ++r) {
                const int nw = order[node0 + q * 4 + r];
                float v = P[r] + bi;
                if (RELU) {
                    v = fmaxf(v, 0.f);
                    reinterpret_cast<__hip_bfloat16*>(outp)[(size_t)nw * DOUT + o] =
                        __float2bfloat16(v);
                } else {
                    reinterpret_cast<float*>(outp)[(size_t)nw * DOUT + o] = v;
                }
            }
        }
    } else {
        if (kpart > 0) {
            const int off = ((kpart - 1) * 64 + lane) * 6;
            red[off] = P[0]; red[off + 1] = P[1]; red[off + 2] = P[2]; red[off + 3] = P[3];
        }
        __syncthreads();
        if (kpart == 0) {
#pragma unroll
            for (int w = 0; w < 15; ++w) {
                const int off = (w * 64 + lane) * 6;
                P[0] += red[off]; P[1] += red[off + 1];
                P[2] += red[off + 2]; P[3] += red[off + 3];
            }
            if (m < DOUT) {
                const int o = m;
                const float bi = bias[o];
#pragma unroll
                for (int r = 0; r < 4; ++r) {
                    const int nw = order[node0 + q * 4 + r];
                    reinterpret_cast<float*>(outp)[(size_t)nw * DOUT + o] = P[r] + bi;
                }
            }
        }
    }
}

// ---------------- log_softmax over C=8 ----------------
__global__ void k_lsm(const float* __restrict__ pre, float* __restrict__ out) {
    int n = blockIdx.x * 256 + threadIdx.x;
    if (n < NN) {
        float v[8];
        float mx = -1e30f;
#pragma unroll
        for (int c = 0; c < 8; ++c) { v[c] = pre[n * 8 + c]; mx = fmaxf(mx, v[c]); }
        float s = 0.f;
#pragma unroll
        for (int c = 0; c < 8; ++c) s += expf(v[c] - mx);
        float ls = logf(s);
#pragma unroll
        for (int c = 0; c < 8; ++c) out[n * 8 + c] = v[c] - mx - ls;
    }
}

// ---------------- launch ----------------
extern "C" void kernel_launch(void* const* d_in, const int* in_sizes, int n_in,
                              void* d_out, int out_size, void* d_ws, size_t ws_size,
                              hipStream_t stream) {
    const float* x     = (const float*)d_in[0];
    const int*   eidx  = (const int*)d_in[1];
    const int*   etype = (const int*)d_in[2];
    const float* bases0 = (const float*)d_in[3];
    const float* comp0  = (const float*)d_in[4];
    const float* root0  = (const float*)d_in[5];
    const float* bias0  = (const float*)d_in[6];
    const float* bases1 = (const float*)d_in[7];
    const float* comp1  = (const float*)d_in[8];
    const float* root1  = (const float*)d_in[9];
    const float* bias1  = (const float*)d_in[10];
    const float* bases2 = (const float*)d_in[11];
    const float* comp2  = (const float*)d_in[12];
    const float* root2  = (const float*)d_in[13];
    const float* bias2  = (const float*)d_in[14];
    const int* srcp = eidx;
    const int* dstp = eidx + EE;

    char* p = (char*)d_ws;
    auto carve = [&](size_t bytes) -> char* {
        char* r = p;
        p += (bytes + 255) & ~(size_t)255;
        return r;
    };
    int*  cnt    = (int*)carve((size_t)NN * RR * sizeof(int));   // 10 MB
    int*  dcount = (int*)carve((size_t)NN * sizeof(int));
    int*  cursor = (int*)carve((size_t)NN * sizeof(int));
    int*  doff   = (int*)carve((size_t)NN * sizeof(int));
    int*  bsum   = (int*)carve(256 * sizeof(int));
    int*  dbin   = (int*)carve(256 * sizeof(int));
    int*  dcur   = (int*)carve(256 * sizeof(int));
    int*  order  = (int*)carve((size_t)NN * sizeof(int));
    int2* ep2    = (int2*)carve((size_t)EPAD * sizeof(int2));    // ~11.2 MB
    __hip_bfloat16* h0 = (__hip_bfloat16*)carve((size_t)NN * DIN * 2);
    __hip_bfloat16* h1 = (__hip_bfloat16*)carve((size_t)NN * DIN * 2);
    __hip_bfloat16* h2 = (__hip_bfloat16*)carve((size_t)NN * DIN * 2);
    float* pre = (float*)carve((size_t)NN * 8 * sizeof(float));
    short* wtA = (short*)carve((size_t)144 * KTOT * sizeof(short));
    __half* cpA = (__half*)carve((size_t)3 * RR * CPAD * sizeof(__half));

    // cnt, dcount, cursor adjacent -> one memset
    hipMemsetAsync(cnt, 0, (size_t)NN * (RR + 2) * sizeof(int) + 512, stream);
    hipMemsetAsync(dbin, 0, 2048, stream);
    // ghost record slots must be zero (a=0 -> exact no-op edges)
    hipMemsetAsync(ep2, 0, (size_t)EPAD * sizeof(int2), stream);

    const int EB = (EE + 255) / 256;   // 3907
    const int NB = (NN + 255) / 256;   // 196
    k_hist<<<EB, 256, 0, stream>>>(dstp, etype, cnt);
    k_scan1<<<NB, 256, 0, stream>>>(cnt, dcount, doff, bsum);
    k_scan2<<<1, 256, 0, stream>>>(bsum, NB);
    k_scan3<<<NB, 256, 0, stream>>>(doff, bsum);
    k_scatter<<<EB, 256, 0, stream>>>(srcp, dstp, etype, cnt, doff, cursor, ep2);
    k_deghist<<<NB, 256, 0, stream>>>(dcount, dbin);
    k_degscan<<<1, 256, 0, stream>>>(dbin);
    k_degscatter<<<NB, 256, 0, stream>>>(dcount, dbin, dcur, order);
    k_cast_x<<<(NN * DIN / 4 + 255) / 256, 256, 0, stream>>>(x, h0);
    k_prep_comp3<<<(3 * RR * CPAD + 255) / 256, 256, 0, stream>>>(comp0, comp1, comp2, cpA);
    k_prep_w3<<<(144 * KTOT + 255) / 256, 256, 0, stream>>>(bases0, root0, bases1, root1,
                                                            bases2, root2, wtA);

    short* wt0 = wtA;
    short* wt1 = wtA + (size_t)64 * KTOT;
    short* wt2 = wtA + (size_t)128 * KTOT;
    __half* cp0 = cpA;
    __half* cp1 = cpA + RR * CPAD;
    __half* cp2 = cpA + 2 * RR * CPAD;

    const int NF = NN / NBW;   // 3125 (exact)
    k_fused<64, true ><<<NF, 1024, 0, stream>>>(h0, ep2, doff, dcount, order, cp0, wt0, bias0, (void*)h1);
    k_fused<64, true ><<<NF, 1024, 0, stream>>>(h1, ep2, doff, dcount, order, cp1, wt1, bias1, (void*)h2);
    k_fused<8,  false><<<NF, 1024, 0, stream>>>(h2, ep2, doff, dcount, order, cp2, wt2, bias2, (void*)pre);
    k_lsm<<<NB, 256, 0, stream>>>(pre, (float*)d_out);
}

// Round 11
// 563.796 us; speedup vs baseline: 1.0920x; 1.0553x over previous
//
#include <hip/hip_runtime.h>
#include <hip/hip_bf16.h>
#include <hip/hip_fp16.h>
#include <stdint.h>

// Problem constants (fixed by the reference)
#define NN   50000
#define RR   50
#define BB   30
#define DIN  64
#define EE   1000000
#define KTOT (BB*DIN + DIN)   // 1984 = 62*32
#define NBW  16               // nodes per workgroup; 50000 = 3125*16 exactly
#define ROWE (KTOT + 8)       // padded LDS row: 1992 elems (3984 B)
#define CPAD 32               // comp row padded 30 -> 32 halves (64 B)
#define EPAD (EE + 8*NN + 32) // ep2 entries incl. per-node 8-alignment ghosts

typedef __attribute__((ext_vector_type(8))) short short8;
typedef __attribute__((ext_vector_type(4))) float floatx4;

#define RFL(x) __builtin_amdgcn_readfirstlane(x)

// ---------------- preprocessing: counting sort of edges by dst ----------------

__global__ void k_hist(const int* __restrict__ dst, const int* __restrict__ et,
                       int* __restrict__ cnt) {
    int e = blockIdx.x * 256 + threadIdx.x;
    if (e < EE) {
        int d = dst[e], r = et[e];
        atomicAdd(&cnt[d * RR + r], 1);
    }
}

// derive dcount from cnt rows; PAD each node's segment to a multiple of 8
__global__ void k_scan1(const int* __restrict__ cnt, int* __restrict__ dcount,
                        int* __restrict__ doff, int* __restrict__ bsum) {
    __shared__ int sh[256];
    int t = threadIdx.x;
    int i = blockIdx.x * 256 + t;
    int vp = 0;
    if (i < NN) {
        const int* c = cnt + (size_t)i * RR;
        int v = 0;
#pragma unroll
        for (int r = 0; r < RR; ++r) v += c[r];
        vp = (v + 7) & ~7;
        dcount[i] = vp;
    }
    sh[t] = vp;
    __syncthreads();
    for (int s = 1; s < 256; s <<= 1) {
        int add = (t >= s) ? sh[t - s] : 0;
        __syncthreads();
        sh[t] += add;
        __syncthreads();
    }
    int incl = sh[t];
    if (i < NN) doff[i] = incl - vp;
    if (t == 255) bsum[blockIdx.x] = incl;
}

__global__ void k_scan2(int* __restrict__ bsum, int nbv) {
    __shared__ int sh[256];
    int t = threadIdx.x;
    int v = (t < nbv) ? bsum[t] : 0;
    sh[t] = v;
    __syncthreads();
    for (int s = 1; s < 256; s <<= 1) {
        int add = (t >= s) ? sh[t - s] : 0;
        __syncthreads();
        sh[t] += add;
        __syncthreads();
    }
    if (t < nbv) bsum[t] = sh[t] - v;
}

__global__ void k_scan3(int* __restrict__ doff, const int* __restrict__ bsum) {
    int i = blockIdx.x * 256 + threadIdx.x;
    if (i < NN) doff[i] += bsum[blockIdx.x];
}

// records: .x = src | (rel<<16)  (src<65536, rel<50), .y = bits of a = 1/cnt(d,r)
__global__ void k_scatter(const int* __restrict__ src, const int* __restrict__ dst,
                          const int* __restrict__ et, const int* __restrict__ cnt,
                          const int* __restrict__ doff, int* __restrict__ cursor,
                          int2* __restrict__ ep2) {
    int e = blockIdx.x * 256 + threadIdx.x;
    if (e < EE) {
        int d = dst[e], r = et[e], s = src[e];
        int p = doff[d] + atomicAdd(&cursor[d], 1);
        float a = 1.0f / (float)cnt[d * RR + r];
        ep2[p] = make_int2(s | (r << 16), __float_as_int(a));
    }
}

// ---------------- degree counting-sort (descending) for wave balance ----------
// LDS-aggregated two-level histograms (<=256 global atomics per block).

__global__ void k_deghist(const int* __restrict__ dcount, int* __restrict__ dbin) {
    __shared__ int lh[256];
    int t = threadIdx.x;
    int i = blockIdx.x * 256 + t;
    lh[t] = 0;
    __syncthreads();
    if (i < NN) {
        int d = dcount[i]; d = (d > 255) ? 255 : d;
        atomicAdd(&lh[255 - d], 1);
    }
    __syncthreads();
    if (lh[t]) atomicAdd(&dbin[t], lh[t]);
}

__global__ void k_degscan(int* __restrict__ dbin) {
    __shared__ int sh[256];
    int t = threadIdx.x;
    int v = dbin[t];
    sh[t] = v;
    __syncthreads();
    for (int s = 1; s < 256; s <<= 1) {
        int add = (t >= s) ? sh[t - s] : 0;
        __syncthreads();
        sh[t] += add;
        __syncthreads();
    }
    dbin[t] = sh[t] - v;
}

__global__ void k_degscatter(const int* __restrict__ dcount, const int* __restrict__ dbin,
                             int* __restrict__ dcur, int* __restrict__ order) {
    __shared__ int lh[256], lbase[256];
    int t = threadIdx.x;
    int i = blockIdx.x * 256 + t;
    lh[t] = 0;
    __syncthreads();
    int b = 0, lpos = 0;
    if (i < NN) {
        int d = dcount[i]; d = (d > 255) ? 255 : d;
        b = 255 - d;
        lpos = atomicAdd(&lh[b], 1);
    }
    __syncthreads();
    lbase[t] = lh[t] ? atomicAdd(&dcur[t], lh[t]) : 0;
    __syncthreads();
    if (i < NN) order[dbin[b] + lbase[b] + lpos] = i;
}

__global__ void k_cast_x(const float* __restrict__ x, __hip_bfloat16* __restrict__ h) {
    int i = blockIdx.x * 256 + threadIdx.x;     // processes 4 elems
    if (i < NN * DIN / 4) {
        float4 v = reinterpret_cast<const float4*>(x)[i];
        ushort4 o;
        o.x = (ushort)(__bfloat16_as_ushort(__float2bfloat16(v.x)));
        o.y = (ushort)(__bfloat16_as_ushort(__float2bfloat16(v.y)));
        o.z = (ushort)(__bfloat16_as_ushort(__float2bfloat16(v.z)));
        o.w = (ushort)(__bfloat16_as_ushort(__float2bfloat16(v.w)));
        reinterpret_cast<ushort4*>(h)[i] = o;
    }
}

// all 3 layers' comp [R,30] fp32 -> padded f16 [3][R,32]
__global__ void k_prep_comp3(const float* __restrict__ c0, const float* __restrict__ c1,
                             const float* __restrict__ c2, __half* __restrict__ cp) {
    int idx = blockIdx.x * 256 + threadIdx.x;
    if (idx < 3 * RR * CPAD) {
        int l = idx / (RR * CPAD);
        int rem = idx - l * (RR * CPAD);
        int r = rem / CPAD, i = rem - r * CPAD;
        const float* c = (l == 0) ? c0 : (l == 1) ? c1 : c2;
        cp[idx] = (i < BB) ? __float2half(c[r * BB + i]) : __float2half(0.f);
    }
}

// all 3 layers' transposed bf16 weights
__global__ void k_prep_w3(const float* __restrict__ b0, const float* __restrict__ r0,
                          const float* __restrict__ b1, const float* __restrict__ r1,
                          const float* __restrict__ b2, const float* __restrict__ r2,
                          short* __restrict__ wt) {
    int idx = blockIdx.x * 256 + threadIdx.x;
    if (idx >= 144 * KTOT) return;
    int row = idx / KTOT, k = idx - row * KTOT;
    const float* bs; const float* rt; int o, dout;
    if (row < 64)       { bs = b0; rt = r0; o = row;        dout = 64; }
    else if (row < 128) { bs = b1; rt = r1; o = row - 64;   dout = 64; }
    else                { bs = b2; rt = r2; o = row - 128;  dout = 8;  }
    float v = 0.f;
    if (o < dout)
        v = (k < BB * DIN) ? bs[k * dout + o] : rt[(k - BB * DIN) * dout + o];
    __hip_bfloat16 hb = __float2bfloat16(v);
    wt[idx] = *reinterpret_cast<const short*>(&hb);
}

// ---------------- fused per-layer kernel ----------------
// SCALAR-PIPE MODEL, clean re-test (R10 was spill-contaminated: WRITE 40 MB,
// SGPR cap hit by 3-stage records (48 SGPR) + VGPR blow-up from hoisted
// cross-edge ds_read batches). Pressure fixes:
//  * 2-stage record rotation (32 SGPR): A = FMA-current chunk, B = gather-next
//    chunk; B reloaded at body end for chunk t+2 (same load->consume distance
//    as R7's 3-stage: one loop body).
//  * EDGE split into two half-rows (2x ds_read_b128 -> 8 hfma2 -> 2x -> 8)
//    with sched_barrier(0) per edge: comp temps capped ~16 VGPR, no
//    cross-edge hoisting.
// comp f16 [50][32] in LDS (3.2 KB): per-edge comp reads are wave-uniform
// ds_read_b128 broadcasts (conflict-free, in-order) instead of s_loads on the
// CU's single scalar unit. Everything else = R7 (bf16 activations, f16 acc,
// 8-edge ghost-padded segments, degree sort). Phase 2 unchanged.

#define LOADR8(u, R0, R1, R2, R3) do {                                          \
    const int _u = ((u) < nit) ? (u) : (nit - 1);                               \
    R0 = rec4[4 * _u];     R1 = rec4[4 * _u + 1];                               \
    R2 = rec4[4 * _u + 2]; R3 = rec4[4 * _u + 3];                               \
} while (0)

#define GATH1(sx) ((unsigned)xin16[((sx) & 0xFFFF) * DIN + lane])

// one edge: comp row from LDS in two b128 pairs + 16 hfma2, f16 acc;
// sched_barrier caps temp pressure and stops cross-edge ds_read hoisting.
#define EDGE_FMA1(_sx, _ai, _g) do {                                            \
    const int4* _cr = (const int4*)(compL + (((unsigned)(_sx)) >> 16) * CPAD);  \
    const float _xvf = __uint_as_float((unsigned)(_g) << 16) * __int_as_float(_ai); \
    const __half _xh = __float2half(_xvf);                                      \
    const __half2 _xv2 = __halves2half2(_xh, _xh);                              \
    int4 _m0 = _cr[0], _m1 = _cr[1];                                            \
    {                                                                           \
        const __half2* _p0 = reinterpret_cast<const __half2*>(&_m0);            \
        const __half2* _p1 = reinterpret_cast<const __half2*>(&_m1);            \
        acc[0] = __hfma2(_p0[0], _xv2, acc[0]);                                 \
        acc[1] = __hfma2(_p0[1], _xv2, acc[1]);                                 \
        acc[2] = __hfma2(_p0[2], _xv2, acc[2]);                                 \
        acc[3] = __hfma2(_p0[3], _xv2, acc[3]);                                 \
        acc[4] = __hfma2(_p1[0], _xv2, acc[4]);                                 \
        acc[5] = __hfma2(_p1[1], _xv2, acc[5]);                                 \
        acc[6] = __hfma2(_p1[2], _xv2, acc[6]);                                 \
        acc[7] = __hfma2(_p1[3], _xv2, acc[7]);                                 \
    }                                                                           \
    int4 _m2 = _cr[2], _m3 = _cr[3];                                            \
    {                                                                           \
        const __half2* _p2 = reinterpret_cast<const __half2*>(&_m2);            \
        const __half2* _p3 = reinterpret_cast<const __half2*>(&_m3);            \
        acc[8]  = __hfma2(_p2[0], _xv2, acc[8]);                                \
        acc[9]  = __hfma2(_p2[1], _xv2, acc[9]);                                \
        acc[10] = __hfma2(_p2[2], _xv2, acc[10]);                               \
        acc[11] = __hfma2(_p2[3], _xv2, acc[11]);                               \
        acc[12] = __hfma2(_p3[0], _xv2, acc[12]);                               \
        acc[13] = __hfma2(_p3[1], _xv2, acc[13]);                               \
        acc[14] = __hfma2(_p3[2], _xv2, acc[14]);                               \
        acc[15] = __hfma2(_p3[3], _xv2, acc[15]);                               \
    }                                                                           \
    __builtin_amdgcn_sched_barrier(0);                                          \
} while (0)

template <int DOUT, bool RELU>
__global__ __launch_bounds__(1024, 8)
void k_fused(const __hip_bfloat16* __restrict__ xin,
             const int2* __restrict__ ep2,
             const int* __restrict__ doff, const int* __restrict__ dcount,
             const int* __restrict__ order,
             const __half* __restrict__ compH,   // [R, 32] f16 padded (global)
             const short* __restrict__ Wt,       // [DPAD][KTOT] bf16 (transposed)
             const float* __restrict__ bias,     // [DOUT]
             void* __restrict__ outp) {
    __shared__ __align__(16) char smem_raw[NBW * ROWE * 2];   // 63744 B
    __shared__ __align__(16) __half compL[RR * CPAD];          // 3200 B
    auto t_tile = reinterpret_cast<__hip_bfloat16(*)[ROWE]>(smem_raw);
    const unsigned short* xin16 = reinterpret_cast<const unsigned short*>(xin);
    const int tid  = threadIdx.x;
    const int lane = tid & 63;
    const int wv   = RFL(tid >> 6);          // 0..15
    const int node0 = blockIdx.x * NBW;

    // stage comp into LDS (one pass; 1600 halves over 1024 threads)
    if (tid < RR * CPAD / 2)
        reinterpret_cast<__half2*>(compL)[tid] =
            reinterpret_cast<const __half2*>(compH)[tid];

    const int n   = RFL(order[node0 + wv]);
    const int beg = RFL(doff[n]);            // multiple of 8
    const int nit = RFL(dcount[n]) >> 3;     // 8-edge iterations
    const unsigned selfb = GATH1(n);         // self row (issued early)

    __syncthreads();                          // compL ready

    // ---- phase 1: one node per wave, 8-edge pipelined iterations ----
    {
        __half2 acc[16];
#pragma unroll
        for (int u = 0; u < 16; ++u)
            acc[u] = __halves2half2(__float2half(0.f), __float2half(0.f));

        if (nit > 0) {
            const int4* rec4 = (const int4*)(ep2 + beg);   // uniform -> s_load
            // 2-stage record rotation: A = chunk t (FMA), B = chunk t+1 (gather)
            int4 A0, A1, A2, A3, B0, B1, B2, B3;
            LOADR8(0, A0, A1, A2, A3);
            LOADR8(1, B0, B1, B2, B3);
            // gathers for chunk 0 (records in A)
            unsigned g0 = GATH1(RFL(A0.x)), g1 = GATH1(RFL(A0.z));
            unsigned g2 = GATH1(RFL(A1.x)), g3 = GATH1(RFL(A1.z));
            unsigned g4 = GATH1(RFL(A2.x)), g5 = GATH1(RFL(A2.z));
            unsigned g6 = GATH1(RFL(A3.x)), g7 = GATH1(RFL(A3.z));

            for (int t = 0; t < nit; ++t) {
                // gathers for chunk t+1 (records in B, loaded last iter)
                unsigned h0 = GATH1(RFL(B0.x)), h1 = GATH1(RFL(B0.z));
                unsigned h2 = GATH1(RFL(B1.x)), h3 = GATH1(RFL(B1.z));
                unsigned h4 = GATH1(RFL(B2.x)), h5 = GATH1(RFL(B2.z));
                unsigned h6 = GATH1(RFL(B3.x)), h7 = GATH1(RFL(B3.z));
                // 8 edges of chunk t (comp from LDS, barrier per edge)
                EDGE_FMA1(RFL(A0.x), RFL(A0.y), g0);
                EDGE_FMA1(RFL(A0.z), RFL(A0.w), g1);
                EDGE_FMA1(RFL(A1.x), RFL(A1.y), g2);
                EDGE_FMA1(RFL(A1.z), RFL(A1.w), g3);
                EDGE_FMA1(RFL(A2.x), RFL(A2.y), g4);
                EDGE_FMA1(RFL(A2.z), RFL(A2.w), g5);
                EDGE_FMA1(RFL(A3.x), RFL(A3.y), g6);
                EDGE_FMA1(RFL(A3.z), RFL(A3.w), g7);
                // rotate: A <- B, then load records for chunk t+2 into B
                A0 = B0; A1 = B1; A2 = B2; A3 = B3;
                LOADR8(t + 2, B0, B1, B2, B3);
                g0 = h0; g1 = h1; g2 = h2; g3 = h3;
                g4 = h4; g5 = h5; g6 = h6; g7 = h7;
            }
        }
#pragma unroll
        for (int b = 0; b < BB; ++b) {
            const float v = (b & 1) ? __high2float(acc[b >> 1]) : __low2float(acc[b >> 1]);
            t_tile[wv][b * DIN + lane] = __float2bfloat16(v);
        }
        t_tile[wv][BB * DIN + lane] =
            __float2bfloat16(__uint_as_float(selfb << 16));
    }
    __syncthreads();

    // ---- phase 2: MFMA 16x16x32 bf16, K = 1984 (62 steps) over 16 waves ----
    const int m = lane & 15;
    const int q = lane >> 4;
    int kk0, nsteps, col_base, kpart;
    if (DOUT == 64) {
        kpart = wv >> 2;                 // 0..3
        col_base = (wv & 3) * 16;
        kk0    = (kpart <= 1) ? kpart * 16 : (kpart == 2 ? 32 : 47);
        nsteps = (kpart <= 1) ? 16 : 15;
    } else {
        kpart = wv;                      // 0..15
        col_base = 0;
        kk0    = (kpart < 14) ? kpart * 4 : (kpart == 14 ? 56 : 59);
        nsteps = (kpart < 14) ? 4 : 3;
    }
    const __hip_bfloat16* arow = &t_tile[m][q * 8];
    const short* brow = Wt + (size_t)(col_base + m) * KTOT + q * 8;

    floatx4 acc0 = {0.f, 0.f, 0.f, 0.f};
    floatx4 acc1 = {0.f, 0.f, 0.f, 0.f};
    int s = 0;
    for (; s + 2 <= nsteps; s += 2) {
        const int kk = kk0 + s;
        short8 a0 = *reinterpret_cast<const short8*>(arow + kk * 32);
        short8 b0 = *reinterpret_cast<const short8*>(brow + kk * 32);
        short8 a1 = *reinterpret_cast<const short8*>(arow + (kk + 1) * 32);
        short8 b1 = *reinterpret_cast<const short8*>(brow + (kk + 1) * 32);
        acc0 = __builtin_amdgcn_mfma_f32_16x16x32_bf16(a0, b0, acc0, 0, 0, 0);
        acc1 = __builtin_amdgcn_mfma_f32_16x16x32_bf16(a1, b1, acc1, 0, 0, 0);
    }
    if (s < nsteps) {
        const int kk = kk0 + s;
        short8 a0 = *reinterpret_cast<const short8*>(arow + kk * 32);
        short8 b0 = *reinterpret_cast<const short8*>(brow + kk * 32);
        acc0 = __builtin_amdgcn_mfma_f32_16x16x32_bf16(a0, b0, acc0, 0, 0, 0);
    }
    floatx4 P = acc0 + acc1;

    __syncthreads();                       // all t_tile reads done
    float* red = (float*)smem_raw;         // reuse LDS; stride-6 layout

    if (DOUT == 64) {
        if (kpart > 0) {
            const int slot = (wv & 3) * 3 + (kpart - 1);   // 0..11
            const int off = (slot * 64 + lane) * 6;
            red[off] = P[0]; red[off + 1] = P[1]; red[off + 2] = P[2]; red[off + 3] = P[3];
        }
        __syncthreads();
        if (kpart == 0) {
#pragma unroll
            for (int t = 0; t < 3; ++t) {
                const int off = (((wv & 3) * 3 + t) * 64 + lane) * 6;
                P[0] += red[off]; P[1] += red[off + 1];
                P[2] += red[off + 2]; P[3] += red[off + 3];
            }
            const int o = col_base + m;
            const float bi = bias[o];
#pragma unroll
            for (int r = 0; r < 4; ++r) {
                const int nw = order[node0 + q * 4 + r];
                float v = P[r] + bi;
                if (RELU) {
                    v = fmaxf(v, 0.f);
                    reinterpret_cast<__hip_bfloat16*>(outp)[(size_t)nw * DOUT + o] =
                        __float2bfloat16(v);
                } else {
                    reinterpret_cast<float*>(outp)[(size_t)nw * DOUT + o] = v;
                }
            }
        }
    } else {
        if (kpart > 0) {
            const int off = ((kpart - 1) * 64 + lane) * 6;
            red[off] = P[0]; red[off + 1] = P[1]; red[off + 2] = P[2]; red[off + 3] = P[3];
        }
        __syncthreads();
        if (kpart == 0) {
#pragma unroll
            for (int w = 0; w < 15; ++w) {
                const int off = (w * 64 + lane) * 6;
                P[0] += red[off]; P[1] += red[off + 1];
                P[2] += red[off + 2]; P[3] += red[off + 3];
            }
            if (m < DOUT) {
                const int o = m;
                const float bi = bias[o];
#pragma unroll
                for (int r = 0; r < 4; ++r) {
                    const int nw = order[node0 + q * 4 + r];
                    reinterpret_cast<float*>(outp)[(size_t)nw * DOUT + o] = P[r] + bi;
                }
            }
        }
    }
}

// ---------------- log_softmax over C=8 ----------------
__global__ void k_lsm(const float* __restrict__ pre, float* __restrict__ out) {
    int n = blockIdx.x * 256 + threadIdx.x;
    if (n < NN) {
        float v[8];
        float mx = -1e30f;
#pragma unroll
        for (int c = 0; c < 8; ++c) { v[c] = pre[n * 8 + c]; mx = fmaxf(mx, v[c]); }
        float s = 0.f;
#pragma unroll
        for (int c = 0; c < 8; ++c) s += expf(v[c] - mx);
        float ls = logf(s);
#pragma unroll
        for (int c = 0; c < 8; ++c) out[n * 8 + c] = v[c] - mx - ls;
    }
}

// ---------------- launch ----------------
extern "C" void kernel_launch(void* const* d_in, const int* in_sizes, int n_in,
                              void* d_out, int out_size, void* d_ws, size_t ws_size,
                              hipStream_t stream) {
    const float* x     = (const float*)d_in[0];
    const int*   eidx  = (const int*)d_in[1];
    const int*   etype = (const int*)d_in[2];
    const float* bases0 = (const float*)d_in[3];
    const float* comp0  = (const float*)d_in[4];
    const float* root0  = (const float*)d_in[5];
    const float* bias0  = (const float*)d_in[6];
    const float* bases1 = (const float*)d_in[7];
    const float* comp1  = (const float*)d_in[8];
    const float* root1  = (const float*)d_in[9];
    const float* bias1  = (const float*)d_in[10];
    const float* bases2 = (const float*)d_in[11];
    const float* comp2  = (const float*)d_in[12];
    const float* root2  = (const float*)d_in[13];
    const float* bias2  = (const float*)d_in[14];
    const int* srcp = eidx;
    const int* dstp = eidx + EE;

    char* p = (char*)d_ws;
    auto carve = [&](size_t bytes) -> char* {
        char* r = p;
        p += (bytes + 255) & ~(size_t)255;
        return r;
    };
    int*  cnt    = (int*)carve((size_t)NN * RR * sizeof(int));   // 10 MB
    int*  dcount = (int*)carve((size_t)NN * sizeof(int));
    int*  cursor = (int*)carve((size_t)NN * sizeof(int));
    int*  doff   = (int*)carve((size_t)NN * sizeof(int));
    int*  bsum   = (int*)carve(256 * sizeof(int));
    int*  dbin   = (int*)carve(256 * sizeof(int));
    int*  dcur   = (int*)carve(256 * sizeof(int));
    int*  order  = (int*)carve((size_t)NN * sizeof(int));
    int2* ep2    = (int2*)carve((size_t)EPAD * sizeof(int2));    // ~11.2 MB
    __hip_bfloat16* h0 = (__hip_bfloat16*)carve((size_t)NN * DIN * 2);
    __hip_bfloat16* h1 = (__hip_bfloat16*)carve((size_t)NN * DIN * 2);
    __hip_bfloat16* h2 = (__hip_bfloat16*)carve((size_t)NN * DIN * 2);
    float* pre = (float*)carve((size_t)NN * 8 * sizeof(float));
    short* wtA = (short*)carve((size_t)144 * KTOT * sizeof(short));
    __half* cpA = (__half*)carve((size_t)3 * RR * CPAD * sizeof(__half));

    // cnt, dcount, cursor adjacent -> one memset
    hipMemsetAsync(cnt, 0, (size_t)NN * (RR + 2) * sizeof(int) + 512, stream);
    hipMemsetAsync(dbin, 0, 2048, stream);
    // ghost record slots must be zero (a=0 -> exact no-op edges)
    hipMemsetAsync(ep2, 0, (size_t)EPAD * sizeof(int2), stream);

    const int EB = (EE + 255) / 256;   // 3907
    const int NB = (NN + 255) / 256;   // 196
    k_hist<<<EB, 256, 0, stream>>>(dstp, etype, cnt);
    k_scan1<<<NB, 256, 0, stream>>>(cnt, dcount, doff, bsum);
    k_scan2<<<1, 256, 0, stream>>>(bsum, NB);
    k_scan3<<<NB, 256, 0, stream>>>(doff, bsum);
    k_scatter<<<EB, 256, 0, stream>>>(srcp, dstp, etype, cnt, doff, cursor, ep2);
    k_deghist<<<NB, 256, 0, stream>>>(dcount, dbin);
    k_degscan<<<1, 256, 0, stream>>>(dbin);
    k_degscatter<<<NB, 256, 0, stream>>>(dcount, dbin, dcur, order);
    k_cast_x<<<(NN * DIN / 4 + 255) / 256, 256, 0, stream>>>(x, h0);
    k_prep_comp3<<<(3 * RR * CPAD + 255) / 256, 256, 0, stream>>>(comp0, comp1, comp2, cpA);
    k_prep_w3<<<(144 * KTOT + 255) / 256, 256, 0, stream>>>(bases0, root0, bases1, root1,
                                                            bases2, root2, wtA);

    short* wt0 = wtA;
    short* wt1 = wtA + (size_t)64 * KTOT;
    short* wt2 = wtA + (size_t)128 * KTOT;
    __half* cp0 = cpA;
    __half* cp1 = cpA + RR * CPAD;
    __half* cp2 = cpA + 2 * RR * CPAD;

    const int NF = NN / NBW;   // 3125 (exact)
    k_fused<64, true ><<<NF, 1024, 0, stream>>>(h0, ep2, doff, dcount, order, cp0, wt0, bias0, (void*)h1);
    k_fused<64, true ><<<NF, 1024, 0, stream>>>(h1, ep2, doff, dcount, order, cp1, wt1, bias1, (void*)h2);
    k_fused<8,  false><<<NF, 1024, 0, stream>>>(h2, ep2, doff, dcount, order, cp2, wt2, bias2, (void*)pre);
    k_lsm<<<NB, 256, 0, stream>>>(pre, (float*)d_out);
}